// Round 9
// baseline (401.915 us; speedup 1.0000x reference)
//
#include <hip/hip_runtime.h>
#include <math.h>

typedef unsigned short u16;
typedef unsigned int u32;
typedef _Float16 f16x8 __attribute__((ext_vector_type(8)));
typedef float f32x16 __attribute__((ext_vector_type(16)));
typedef u16 u16x4 __attribute__((ext_vector_type(4)));

__device__ __forceinline__ u16 f2h(float x) {
  _Float16 h = (_Float16)x;
  return __builtin_bit_cast(u16, h);
}
__device__ __forceinline__ float h2f(u16 u) {
  return (float)__builtin_bit_cast(_Float16, u);
}

// exact-erf GELU via Abramowitz-Stegun 7.1.26 (|err| <= 1.5e-7)
__device__ __forceinline__ float gelu_erf(float x) {
  const float u = x * 0.70710678118654752f;
  const float s = fabsf(u);
  const float t = __frcp_rn(1.0f + 0.3275911f * s);
  float p = 1.061405429f;
  p = p * t - 1.453152027f;
  p = p * t + 1.421413741f;
  p = p * t - 0.284496736f;
  p = p * t + 0.254829592f;
  const float e = __expf(-s * s);
  float erf = 1.0f - p * t * e;
  erf = u < 0.0f ? -erf : erf;
  return 0.5f * x * (1.0f + erf);
}

__device__ __forceinline__ void gload16(const void* g, void* l) {
  __builtin_amdgcn_global_load_lds(
      (const __attribute__((address_space(1))) void*)g,
      (__attribute__((address_space(3))) void*)l, 16, 0, 0);
}

// ---------------------------------------------------------------------------
// m97-style NT GEMM, fp16, now on mfma_f32_32x32x16_f16 (higher ceiling,
// half the MFMA instruction count vs 16x16x32 at identical LDS traffic).
// A [M,lda] rm, B [N,ldb] rm, C[m][n] = sum_k A[m][k]*B[n][k].
// 128x128 tile, BK=64, 4 waves (2x2); wave = 64x64 = 2x2 frags of 32x32.
// A/B frag: row = lane&31, k = (lane>>5)*8+e (family rule, 16x16 analog
// test-verified).  C/D: col = lane&31, row = (reg&3)+8*(reg>>2)+4*(lane>>5)
// [HW-verified m74/m101].  LDS 32KB single-buffer, XOR slot swizzle
// (slot ^= row&7) w/ pre-swizzled global source (0 conflicts, measured).
// EPI: 0 = qkv writer (n<2048 -> qk; else vT[n-2048][m] DIRECT transpose),
//      1 = scores f32, 2 = +resid -> r2 fp16, 3 = +bias+gelu -> fp16,
//      4 = +bias+resid(fp16) -> f32 out
// ---------------------------------------------------------------------------
template <int EPI, bool SWZ>
__global__ __launch_bounds__(256, 4) void gemm_nt(
    const u16* __restrict__ A, const u16* __restrict__ B, int M, int N, int K,
    int lda, int ldb, long zsA, long zsB, long zsC, float* __restrict__ outF,
    u16* __restrict__ outU, u16* __restrict__ outU2,
    const float* __restrict__ aux0, const u16* __restrict__ aux1u) {
  __shared__ char smem[2 * 128 * 64 * 2];  // 32 KiB: sA | sB
  char* sA = smem;
  char* sB = smem + 16384;

  const int tid = threadIdx.x;
  const int lane = tid & 63;
  const int wave = tid >> 6;
  const int z = blockIdx.z;

  int bx = blockIdx.x, by = blockIdx.y;
  if constexpr (SWZ) {
    const int gx = gridDim.x;
    const int nwg = gx * gridDim.y;  // all our per-z grids are %8 == 0
    const int id = by * gx + bx;
    const int q = nwg >> 3;
    const int id2 = (id & 7) * q + (id >> 3);
    bx = id2 % gx;
    by = id2 / gx;
  }
  const long row0 = (long)by * 128;
  const long col0 = (long)bx * 128;

  const u16* __restrict__ Ab = A + (long)z * zsA;
  const u16* __restrict__ Bb = B + (long)z * zsB;

  // staging geometry (pre-swizzled global k-slot, linear LDS dest)
  const int srow = lane >> 3;
  const int sslot = (lane & 7) ^ srow;

  const int ln31 = lane & 31;
  const int hh = lane >> 5;             // k-half selector within frag
  const int wm = (wave >> 1) << 6;
  const int wn = (wave & 1) << 6;

  f32x16 acc[2][2] = {};
  const int nk = K >> 6;

  auto stage = [&](int kt) {
#pragma unroll
    for (int c = 0; c < 4; ++c) {
      const int chunk = wave * 4 + c;  // 0..15, 8 rows each
      const int r = chunk * 8 + srow;
      gload16(Ab + (row0 + r) * (long)lda + kt * 64 + sslot * 8,
              sA + chunk * 1024);
      gload16(Bb + (col0 + r) * (long)ldb + kt * 64 + sslot * 8,
              sB + chunk * 1024);
    }
  };

  stage(0);
  for (int kt = 0; kt < nk; ++kt) {
    __syncthreads();  // drains vmcnt(0) -> staged LDS ready
#pragma unroll
    for (int ks = 0; ks < 4; ++ks) {  // 4 k-steps of 16 within BK=64
      f16x8 af[2], bg[2];
#pragma unroll
      for (int i = 0; i < 2; ++i) {
        const int r = wm + i * 32 + ln31;
        const int slot = ((ks << 1) | hh) ^ (r & 7);
        af[i] = *(const f16x8*)(sA + r * 128 + slot * 16);
      }
#pragma unroll
      for (int j = 0; j < 2; ++j) {
        const int r = wn + j * 32 + ln31;
        const int slot = ((ks << 1) | hh) ^ (r & 7);
        bg[j] = *(const f16x8*)(sB + r * 128 + slot * 16);
      }
#pragma unroll
      for (int i = 0; i < 2; ++i)
#pragma unroll
        for (int j = 0; j < 2; ++j)
          acc[i][j] = __builtin_amdgcn_mfma_f32_32x32x16_f16(af[i], bg[j],
                                                             acc[i][j], 0, 0, 0);
    }
    __syncthreads();
    if (kt + 1 < nk) stage(kt + 1);
  }

  // epilogue: C/D: col = lane&31, row = (reg&3) + 8*(reg>>2) + 4*(lane>>5)
#pragma unroll
  for (int i = 0; i < 2; ++i) {
#pragma unroll
    for (int j = 0; j < 2; ++j) {
      const long n = col0 + wn + j * 32 + ln31;
#pragma unroll
      for (int q = 0; q < 4; ++q) {
        const long mb = row0 + wm + i * 32 + (q << 3) + (hh << 2);
        if constexpr (EPI == 0) {
          if (n < 2048) {
#pragma unroll
            for (int rr = 0; rr < 4; ++rr)
              outU[(mb + rr) * 2048 + n] = f2h(acc[i][j][4 * q + rr]);
          } else {
            // direct V transpose: vT [4][1024][2048], m runs contiguous
            u16x4 V;
#pragma unroll
            for (int rr = 0; rr < 4; ++rr) V[rr] = f2h(acc[i][j][4 * q + rr]);
            *(u16x4*)(outU2 + ((mb >> 11) << 21) + (n - 2048) * 2048 +
                      (mb & 2047)) = V;
          }
        } else if constexpr (EPI == 1) {
#pragma unroll
          for (int rr = 0; rr < 4; ++rr)
            outF[(long)z * zsC + (mb + rr) * (long)N + n] = acc[i][j][4 * q + rr];
        } else if constexpr (EPI == 2) {
#pragma unroll
          for (int rr = 0; rr < 4; ++rr) {
            const long idx = (long)z * zsC + (mb + rr) * (long)N + n;
            outU[idx] = f2h(acc[i][j][4 * q + rr] + aux0[idx]);
          }
        } else if constexpr (EPI == 3) {
          const float b = aux0[n];
#pragma unroll
          for (int rr = 0; rr < 4; ++rr)
            outU[(mb + rr) * (long)N + n] = f2h(gelu_erf(acc[i][j][4 * q + rr] + b));
        } else {
          const float b = aux0[n];
#pragma unroll
          for (int rr = 0; rr < 4; ++rr) {
            const long idx = (mb + rr) * (long)N + n;
            outF[idx] = acc[i][j][4 * q + rr] + b + h2f(aux1u[idx]);
          }
        }
      }
    }
  }
}

// ---------------------------------------------------------------------------
// LayerNorm over D=1024, one wave per row, 4 rows/block, fp16 out.
// F32IN: read f32; else read fp16 (r2 residual stream).
// ---------------------------------------------------------------------------
template <bool F32IN>
__global__ __launch_bounds__(256) void ln_k(const void* __restrict__ xin,
                                            const float* __restrict__ gw,
                                            const float* __restrict__ bw,
                                            u16* __restrict__ out) {
  const int lane = threadIdx.x & 63;
  const int wv = threadIdx.x >> 6;
  const long row = (long)blockIdx.x * 4 + wv;
  float4 v[4];
  float s = 0.f, ss = 0.f;
#pragma unroll
  for (int j = 0; j < 4; ++j) {
    const int n = (lane + 64 * j) * 4;
    if constexpr (F32IN) {
      v[j] = *(const float4*)((const float*)xin + row * 1024 + n);
    } else {
      const u16x4 hv = *(const u16x4*)((const u16*)xin + row * 1024 + n);
      v[j] = make_float4(h2f(hv[0]), h2f(hv[1]), h2f(hv[2]), h2f(hv[3]));
    }
    s += v[j].x + v[j].y + v[j].z + v[j].w;
    ss += v[j].x * v[j].x + v[j].y * v[j].y + v[j].z * v[j].z + v[j].w * v[j].w;
  }
#pragma unroll
  for (int o = 32; o; o >>= 1) {
    s += __shfl_xor(s, o);
    ss += __shfl_xor(ss, o);
  }
  const float mu = s * (1.f / 1024.f);
  const float var = ss * (1.f / 1024.f) - mu * mu;
  const float rs = rsqrtf(var + 1e-5f);
  u16* orow = out + row * 1024;
#pragma unroll
  for (int j = 0; j < 4; ++j) {
    const int n = (lane + 64 * j) * 4;
    const float4 gg = *(const float4*)(gw + n);
    const float4 bb = *(const float4*)(bw + n);
    u16x4 H;
    H[0] = f2h((v[j].x - mu) * rs * gg.x + bb.x);
    H[1] = f2h((v[j].y - mu) * rs * gg.y + bb.y);
    H[2] = f2h((v[j].z - mu) * rs * gg.z + bb.z);
    H[3] = f2h((v[j].w - mu) * rs * gg.w + bb.w);
    *(u16x4*)(orow + n) = H;
  }
}

// ---------------------------------------------------------------------------
// Tiled transpose f32 -> fp16. in [R,C] -> out [C,R].
// ---------------------------------------------------------------------------
__global__ __launch_bounds__(256) void transpose_k(const float* __restrict__ in,
                                                   u16* __restrict__ out,
                                                   int R, int C) {
  __shared__ float tile[32][33];
  const int c0 = blockIdx.x * 32, r0 = blockIdx.y * 32;
#pragma unroll
  for (int i = 0; i < 4; ++i) {
    const int lin = threadIdx.x + 256 * i;
    const int rr = lin >> 5, cc = lin & 31;
    tile[rr][cc] = in[(long)(r0 + rr) * C + c0 + cc];
  }
  __syncthreads();
#pragma unroll
  for (int i = 0; i < 4; ++i) {
    const int lin = threadIdx.x + 256 * i;
    const int oc = lin >> 5, orr = lin & 31;
    out[(long)(c0 + oc) * R + (r0 + orr)] = f2h(tile[orr][oc]);
  }
}

// ---------------------------------------------------------------------------
// Row softmax over 2048 cols, f32 in -> fp16 out IN-PLACE (P overwrites the
// first 4 KB of each 16 KB score row; all reads precede first barrier).
// ---------------------------------------------------------------------------
__global__ __launch_bounds__(256) void softmax_k(float* __restrict__ S) {
  const long row = blockIdx.x;
  float* sr = S + row * 2048;
  u16* pr = (u16*)sr;
  const int tid = threadIdx.x;
  const int lane = tid & 63, wv = tid >> 6;
  __shared__ float red[8];
  const float4 v0 = *(const float4*)(sr + tid * 4);
  const float4 v1 = *(const float4*)(sr + 1024 + tid * 4);
  float mx = fmaxf(fmaxf(fmaxf(v0.x, v0.y), fmaxf(v0.z, v0.w)),
                   fmaxf(fmaxf(v1.x, v1.y), fmaxf(v1.z, v1.w)));
#pragma unroll
  for (int o = 32; o; o >>= 1) mx = fmaxf(mx, __shfl_xor(mx, o));
  if (lane == 0) red[wv] = mx;
  __syncthreads();
  mx = fmaxf(fmaxf(red[0], red[1]), fmaxf(red[2], red[3]));
  float e[8];
  e[0] = __expf(v0.x - mx); e[1] = __expf(v0.y - mx);
  e[2] = __expf(v0.z - mx); e[3] = __expf(v0.w - mx);
  e[4] = __expf(v1.x - mx); e[5] = __expf(v1.y - mx);
  e[6] = __expf(v1.z - mx); e[7] = __expf(v1.w - mx);
  float sm = e[0] + e[1] + e[2] + e[3] + e[4] + e[5] + e[6] + e[7];
#pragma unroll
  for (int o = 32; o; o >>= 1) sm += __shfl_xor(sm, o);
  if (lane == 0) red[4 + wv] = sm;
  __syncthreads();
  sm = red[4] + red[5] + red[6] + red[7];
  const float inv = 1.f / sm;
  u16x4 a, b;
  a[0] = f2h(e[0] * inv); a[1] = f2h(e[1] * inv);
  a[2] = f2h(e[2] * inv); a[3] = f2h(e[3] * inv);
  b[0] = f2h(e[4] * inv); b[1] = f2h(e[5] * inv);
  b[2] = f2h(e[6] * inv); b[3] = f2h(e[7] * inv);
  *(u16x4*)(pr + tid * 4) = a;
  *(u16x4*)(pr + 1024 + tid * 4) = b;
}

// ---------------------------------------------------------------------------
extern "C" void kernel_launch(void* const* d_in, const int* in_sizes, int n_in,
                              void* d_out, int out_size, void* d_ws,
                              size_t ws_size, hipStream_t stream) {
  const float* x     = (const float*)d_in[0];  // [4,2048,1024]
  const float* w_qkv = (const float*)d_in[1];  // [1024,3072]
  const float* fc1_w = (const float*)d_in[2];  // [1024,4096]
  const float* fc1_b = (const float*)d_in[3];  // [4096]
  const float* fc2_w = (const float*)d_in[4];  // [4096,1024]
  const float* fc2_b = (const float*)d_in[5];  // [1024]
  const float* ln1_g = (const float*)d_in[6];
  const float* ln1_b = (const float*)d_in[7];
  const float* ln2_g = (const float*)d_in[8];
  const float* ln2_b = (const float*)d_in[9];
  float* out = (float*)d_out;

  // workspace (phase-aliased; all fp16 unless noted)
  char* ws = (char*)d_ws;
  const long MB = 1024L * 1024L;
  u16*   h    = (u16*)(ws + 0);          // 16MB [8192,1024]
  u16*   wqkT = (u16*)(ws + 16 * MB);    //  6MB [3072,1024]
  float* sc   = (float*)(ws + 0);        // 64MB f32 scores (h,wqkT dead)
  u16*   qk   = (u16*)(ws + 64 * MB);    // 32MB [8192,2048] (q|k)
  u16*   h2   = (u16*)(ws + 96 * MB);    // 16MB
  u16*   vT   = (u16*)(ws + 112 * MB);   // 16MB [4][1024][2048]
  u16*   w1T  = (u16*)(ws + 144 * MB);   //  8MB [4096,1024]
  u16*   w2T  = (u16*)(ws + 152 * MB);   //  8MB [1024,4096]
  u16*   r2   = (u16*)(ws + 160 * MB);   // 16MB fp16 [8192,1024]
  u16*   g    = (u16*)(ws + 0);          // 64MB [8192,4096] (sc/P dead)

  dim3 blk(256);

  // 1) LN1 -> h fp16
  ln_k<true><<<2048, blk, 0, stream>>>(x, ln1_g, ln1_b, h);
  // 2) w_qkv [1024,3072] -> wqkT [3072,1024] fp16
  transpose_k<<<dim3(3072 / 32, 1024 / 32, 1), blk, 0, stream>>>(w_qkv, wqkT,
                                                                 1024, 3072);
  // 3) qkv-GEMM: h @ wqkv^T -> qk (n<2048) + vT DIRECT.  grid 1536.
  gemm_nt<0, true><<<dim3(24, 64, 1), blk, 0, stream>>>(
      h, wqkT, 8192, 3072, 1024, 1024, 1024, 0, 0, 0, nullptr, qk, vT,
      nullptr, nullptr);
  // 4) GEMM2: scores[z] = q[z] @ k[z]^T (K=1024).  grid 256/z.
  gemm_nt<1, true><<<dim3(16, 16, 4), blk, 0, stream>>>(
      qk, qk + 1024, 2048, 2048, 1024, 2048, 2048, 2048L * 2048, 2048L * 2048,
      2048L * 2048, sc, nullptr, nullptr, nullptr, nullptr);
  // 5) softmax in-place: P (fp16, lda=4096 u16) overwrites score rows
  softmax_k<<<8192, blk, 0, stream>>>(sc);
  // 6) GEMM3: attn = P @ vT + resid(x f32) -> r2 fp16.  grid 128/z.
  gemm_nt<2, true><<<dim3(8, 16, 4), blk, 0, stream>>>(
      (const u16*)sc, vT, 2048, 1024, 2048, 4096, 2048, 2048L * 4096,
      1024L * 2048, 2048L * 1024, nullptr, r2, nullptr, x, nullptr);
  // 7) LN2 (fp16 in) -> h2 fp16
  ln_k<false><<<2048, blk, 0, stream>>>(r2, ln2_g, ln2_b, h2);
  // 8) fc1_w -> w1T, fc2_w -> w2T
  transpose_k<<<dim3(4096 / 32, 1024 / 32, 1), blk, 0, stream>>>(fc1_w, w1T,
                                                                 1024, 4096);
  transpose_k<<<dim3(1024 / 32, 4096 / 32, 1), blk, 0, stream>>>(fc2_w, w2T,
                                                                 4096, 1024);
  // 9) GEMM4: g = gelu(h2 @ fc1_w + b1) fp16.  grid 2048.
  gemm_nt<3, true><<<dim3(32, 64, 1), blk, 0, stream>>>(
      h2, w1T, 8192, 4096, 1024, 1024, 1024, 0, 0, 0, nullptr, g, nullptr,
      fc1_b, nullptr);
  // 10) GEMM5: out = g @ fc2_w + b2 + r2(fp16).  grid 512.
  gemm_nt<4, true><<<dim3(8, 64, 1), blk, 0, stream>>>(
      g, w2T, 8192, 1024, 4096, 4096, 4096, 0, 0, 0, out, nullptr, nullptr,
      fc2_b, r2);
}

// Round 10
// 369.662 us; speedup vs baseline: 1.0873x; 1.0873x over previous
//
#include <hip/hip_runtime.h>
#include <math.h>

typedef unsigned short u16;
typedef unsigned int u32;
typedef _Float16 f16x8 __attribute__((ext_vector_type(8)));
typedef float f32x4 __attribute__((ext_vector_type(4)));
typedef u16 u16x4 __attribute__((ext_vector_type(4)));

__device__ __forceinline__ u16 f2h(float x) {
  _Float16 h = (_Float16)x;
  return __builtin_bit_cast(u16, h);
}
__device__ __forceinline__ float h2f(u16 u) {
  return (float)__builtin_bit_cast(_Float16, u);
}

// exact-erf GELU via Abramowitz-Stegun 7.1.26 (|err| <= 1.5e-7)
__device__ __forceinline__ float gelu_erf(float x) {
  const float u = x * 0.70710678118654752f;
  const float s = fabsf(u);
  const float t = __frcp_rn(1.0f + 0.3275911f * s);
  float p = 1.061405429f;
  p = p * t - 1.453152027f;
  p = p * t + 1.421413741f;
  p = p * t - 0.284496736f;
  p = p * t + 0.254829592f;
  const float e = __expf(-s * s);
  float erf = 1.0f - p * t * e;
  erf = u < 0.0f ? -erf : erf;
  return 0.5f * x * (1.0f + erf);
}

__device__ __forceinline__ void gload16(const void* g, void* l) {
  __builtin_amdgcn_global_load_lds(
      (const __attribute__((address_space(1))) void*)g,
      (__attribute__((address_space(3))) void*)l, 16, 0, 0);
}

// ---------------------------------------------------------------------------
// m97-style NT GEMM, fp16, mfma_f32_16x16x32_f16 (the verified engine:
// 0 bank conflicts, ~35% MfmaUtil — R8 measured.  R9's 32x32 shape caused
// 4-way LDS conflicts via the slot swizzle and regressed; reverted).
// A [M,lda] rm, B [N,ldb] rm, C[m][n] = sum_k A[m][k]*B[n][k].
// 128x128 tile, BK=64, 4 waves (2x2); wave = 64x64 = 4x4 frags of 16x16.
// LDS 32KB single-buffer (multi-block/CU overlap hides barrier drain, m114).
// XOR slot swizzle (slot ^= row&7) w/ pre-swizzled global source.
// EPI: 0 = qkv writer (n<2048 -> qk; else vT[z][n-2048][m] DIRECT transpose,
//          packed u16x4 along m),
//      1 = scores f32, 2 = +resid(x f32) -> r2 fp16, 3 = +bias+gelu -> fp16,
//      4 = +bias+resid(fp16) -> f32 out
// ---------------------------------------------------------------------------
template <int EPI, bool SWZ>
__global__ __launch_bounds__(256, 4) void gemm_nt(
    const u16* __restrict__ A, const u16* __restrict__ B, int M, int N, int K,
    int lda, int ldb, long zsA, long zsB, long zsC, float* __restrict__ outF,
    u16* __restrict__ outU, u16* __restrict__ outU2,
    const float* __restrict__ aux0, const u16* __restrict__ aux1u) {
  __shared__ char smem[2 * 128 * 64 * 2];  // 32 KiB: sA | sB
  char* sA = smem;
  char* sB = smem + 16384;

  const int tid = threadIdx.x;
  const int lane = tid & 63;
  const int wave = tid >> 6;
  const int z = blockIdx.z;

  int bx = blockIdx.x, by = blockIdx.y;
  if constexpr (SWZ) {
    const int gx = gridDim.x;
    const int nwg = gx * gridDim.y;  // all our per-z grids are %8 == 0
    const int id = by * gx + bx;
    const int q = nwg >> 3;
    const int id2 = (id & 7) * q + (id >> 3);
    bx = id2 % gx;
    by = id2 / gx;
  }
  const long row0 = (long)by * 128;
  const long col0 = (long)bx * 128;

  const u16* __restrict__ Ab = A + (long)z * zsA;
  const u16* __restrict__ Bb = B + (long)z * zsB;

  // staging geometry (pre-swizzled global k-slot, linear LDS dest)
  const int srow = lane >> 3;
  const int sslot = (lane & 7) ^ srow;

  const int wm = (wave >> 1) << 6;
  const int wn = (wave & 1) << 6;
  const int fr = lane & 15;
  const int kgrp = lane >> 4;

  f32x4 acc[4][4] = {};
  const int nk = K >> 6;

  auto stage = [&](int kt) {
#pragma unroll
    for (int c = 0; c < 4; ++c) {
      const int chunk = wave * 4 + c;  // 0..15, 8 rows each
      const int r = chunk * 8 + srow;
      gload16(Ab + (row0 + r) * (long)lda + kt * 64 + sslot * 8,
              sA + chunk * 1024);
      gload16(Bb + (col0 + r) * (long)ldb + kt * 64 + sslot * 8,
              sB + chunk * 1024);
    }
  };

  stage(0);
  for (int kt = 0; kt < nk; ++kt) {
    __syncthreads();  // drains vmcnt(0) -> staged LDS ready
#pragma unroll
    for (int kk = 0; kk < 2; ++kk) {
      f16x8 af[4], bg[4];
#pragma unroll
      for (int i = 0; i < 4; ++i) {
        const int r = wm + i * 16 + fr;
        const int slot = ((kk << 2) | kgrp) ^ (r & 7);
        af[i] = *(const f16x8*)(sA + r * 128 + slot * 16);
      }
#pragma unroll
      for (int j = 0; j < 4; ++j) {
        const int r = wn + j * 16 + fr;
        const int slot = ((kk << 2) | kgrp) ^ (r & 7);
        bg[j] = *(const f16x8*)(sB + r * 128 + slot * 16);
      }
#pragma unroll
      for (int i = 0; i < 4; ++i)
#pragma unroll
        for (int j = 0; j < 4; ++j)
          acc[i][j] = __builtin_amdgcn_mfma_f32_16x16x32_f16(af[i], bg[j],
                                                             acc[i][j], 0, 0, 0);
    }
    __syncthreads();
    if (kt + 1 < nk) stage(kt + 1);
  }

  // epilogue: C/D frag layout (verified): col = lane&15, row = kgrp*4 + r
#pragma unroll
  for (int i = 0; i < 4; ++i) {
    const long m0 = row0 + wm + i * 16 + (kgrp << 2);  // r=0..3 contiguous
#pragma unroll
    for (int j = 0; j < 4; ++j) {
      const long n = col0 + wn + j * 16 + fr;
      if constexpr (EPI == 0) {
        if (n < 2048) {
#pragma unroll
          for (int r = 0; r < 4; ++r)
            outU[(m0 + r) * 2048 + n] = f2h(acc[i][j][r]);
        } else {
          // direct V transpose: vT [4][1024][2048] fp16, m contiguous
          u16x4 V;
#pragma unroll
          for (int r = 0; r < 4; ++r) V[r] = f2h(acc[i][j][r]);
          *(u16x4*)(outU2 + ((m0 >> 11) << 21) + (n - 2048) * 2048 +
                    (m0 & 2047)) = V;
        }
      } else if constexpr (EPI == 1) {
#pragma unroll
        for (int r = 0; r < 4; ++r)
          outF[(long)z * zsC + (m0 + r) * (long)N + n] = acc[i][j][r];
      } else if constexpr (EPI == 2) {
#pragma unroll
        for (int r = 0; r < 4; ++r) {
          const long idx = (long)z * zsC + (m0 + r) * (long)N + n;
          outU[idx] = f2h(acc[i][j][r] + aux0[idx]);
        }
      } else if constexpr (EPI == 3) {
        const float b = aux0[n];
#pragma unroll
        for (int r = 0; r < 4; ++r)
          outU[(m0 + r) * (long)N + n] = f2h(gelu_erf(acc[i][j][r] + b));
      } else {
        const float b = aux0[n];
#pragma unroll
        for (int r = 0; r < 4; ++r) {
          const long idx = (m0 + r) * (long)N + n;
          outF[idx] = acc[i][j][r] + b + h2f(aux1u[idx]);
        }
      }
    }
  }
}

// ---------------------------------------------------------------------------
// LayerNorm over D=1024, one wave per row, 4 rows/block, fp16 out.
// F32IN: read f32; else read fp16 (r2 residual stream).
// ---------------------------------------------------------------------------
template <bool F32IN>
__global__ __launch_bounds__(256) void ln_k(const void* __restrict__ xin,
                                            const float* __restrict__ gw,
                                            const float* __restrict__ bw,
                                            u16* __restrict__ out) {
  const int lane = threadIdx.x & 63;
  const int wv = threadIdx.x >> 6;
  const long row = (long)blockIdx.x * 4 + wv;
  float4 v[4];
  float s = 0.f, ss = 0.f;
#pragma unroll
  for (int j = 0; j < 4; ++j) {
    const int n = (lane + 64 * j) * 4;
    if constexpr (F32IN) {
      v[j] = *(const float4*)((const float*)xin + row * 1024 + n);
    } else {
      const u16x4 hv = *(const u16x4*)((const u16*)xin + row * 1024 + n);
      v[j] = make_float4(h2f(hv[0]), h2f(hv[1]), h2f(hv[2]), h2f(hv[3]));
    }
    s += v[j].x + v[j].y + v[j].z + v[j].w;
    ss += v[j].x * v[j].x + v[j].y * v[j].y + v[j].z * v[j].z + v[j].w * v[j].w;
  }
#pragma unroll
  for (int o = 32; o; o >>= 1) {
    s += __shfl_xor(s, o);
    ss += __shfl_xor(ss, o);
  }
  const float mu = s * (1.f / 1024.f);
  const float var = ss * (1.f / 1024.f) - mu * mu;
  const float rs = rsqrtf(var + 1e-5f);
  u16* orow = out + row * 1024;
#pragma unroll
  for (int j = 0; j < 4; ++j) {
    const int n = (lane + 64 * j) * 4;
    const float4 gg = *(const float4*)(gw + n);
    const float4 bb = *(const float4*)(bw + n);
    u16x4 H;
    H[0] = f2h((v[j].x - mu) * rs * gg.x + bb.x);
    H[1] = f2h((v[j].y - mu) * rs * gg.y + bb.y);
    H[2] = f2h((v[j].z - mu) * rs * gg.z + bb.z);
    H[3] = f2h((v[j].w - mu) * rs * gg.w + bb.w);
    *(u16x4*)(orow + n) = H;
  }
}

// ---------------------------------------------------------------------------
// Tiled transpose f32 -> fp16. in [R,C] -> out [C,R].
// ---------------------------------------------------------------------------
__global__ __launch_bounds__(256) void transpose_k(const float* __restrict__ in,
                                                   u16* __restrict__ out,
                                                   int R, int C) {
  __shared__ float tile[32][33];
  const int c0 = blockIdx.x * 32, r0 = blockIdx.y * 32;
#pragma unroll
  for (int i = 0; i < 4; ++i) {
    const int lin = threadIdx.x + 256 * i;
    const int rr = lin >> 5, cc = lin & 31;
    tile[rr][cc] = in[(long)(r0 + rr) * C + c0 + cc];
  }
  __syncthreads();
#pragma unroll
  for (int i = 0; i < 4; ++i) {
    const int lin = threadIdx.x + 256 * i;
    const int oc = lin >> 5, orr = lin & 31;
    out[(long)(c0 + oc) * R + (r0 + orr)] = f2h(tile[orr][oc]);
  }
}

// ---------------------------------------------------------------------------
// Row softmax over 2048 cols, f32 in -> fp16 out IN-PLACE (P overwrites the
// first 4 KB of each 16 KB score row; all reads precede first barrier).
// ---------------------------------------------------------------------------
__global__ __launch_bounds__(256) void softmax_k(float* __restrict__ S) {
  const long row = blockIdx.x;
  float* sr = S + row * 2048;
  u16* pr = (u16*)sr;
  const int tid = threadIdx.x;
  const int lane = tid & 63, wv = tid >> 6;
  __shared__ float red[8];
  const float4 v0 = *(const float4*)(sr + tid * 4);
  const float4 v1 = *(const float4*)(sr + 1024 + tid * 4);
  float mx = fmaxf(fmaxf(fmaxf(v0.x, v0.y), fmaxf(v0.z, v0.w)),
                   fmaxf(fmaxf(v1.x, v1.y), fmaxf(v1.z, v1.w)));
#pragma unroll
  for (int o = 32; o; o >>= 1) mx = fmaxf(mx, __shfl_xor(mx, o));
  if (lane == 0) red[wv] = mx;
  __syncthreads();
  mx = fmaxf(fmaxf(red[0], red[1]), fmaxf(red[2], red[3]));
  float e[8];
  e[0] = __expf(v0.x - mx); e[1] = __expf(v0.y - mx);
  e[2] = __expf(v0.z - mx); e[3] = __expf(v0.w - mx);
  e[4] = __expf(v1.x - mx); e[5] = __expf(v1.y - mx);
  e[6] = __expf(v1.z - mx); e[7] = __expf(v1.w - mx);
  float sm = e[0] + e[1] + e[2] + e[3] + e[4] + e[5] + e[6] + e[7];
#pragma unroll
  for (int o = 32; o; o >>= 1) sm += __shfl_xor(sm, o);
  if (lane == 0) red[4 + wv] = sm;
  __syncthreads();
  sm = red[4] + red[5] + red[6] + red[7];
  const float inv = 1.f / sm;
  u16x4 a, b;
  a[0] = f2h(e[0] * inv); a[1] = f2h(e[1] * inv);
  a[2] = f2h(e[2] * inv); a[3] = f2h(e[3] * inv);
  b[0] = f2h(e[4] * inv); b[1] = f2h(e[5] * inv);
  b[2] = f2h(e[6] * inv); b[3] = f2h(e[7] * inv);
  *(u16x4*)(pr + tid * 4) = a;
  *(u16x4*)(pr + 1024 + tid * 4) = b;
}

// ---------------------------------------------------------------------------
extern "C" void kernel_launch(void* const* d_in, const int* in_sizes, int n_in,
                              void* d_out, int out_size, void* d_ws,
                              size_t ws_size, hipStream_t stream) {
  const float* x     = (const float*)d_in[0];  // [4,2048,1024]
  const float* w_qkv = (const float*)d_in[1];  // [1024,3072]
  const float* fc1_w = (const float*)d_in[2];  // [1024,4096]
  const float* fc1_b = (const float*)d_in[3];  // [4096]
  const float* fc2_w = (const float*)d_in[4];  // [4096,1024]
  const float* fc2_b = (const float*)d_in[5];  // [1024]
  const float* ln1_g = (const float*)d_in[6];
  const float* ln1_b = (const float*)d_in[7];
  const float* ln2_g = (const float*)d_in[8];
  const float* ln2_b = (const float*)d_in[9];
  float* out = (float*)d_out;

  // workspace (phase-aliased; all fp16 unless noted)
  char* ws = (char*)d_ws;
  const long MB = 1024L * 1024L;
  u16*   h    = (u16*)(ws + 0);          // 16MB [8192,1024]
  u16*   wqkT = (u16*)(ws + 16 * MB);    //  6MB [3072,1024]
  float* sc   = (float*)(ws + 0);        // 64MB f32 scores (h,wqkT dead)
  u16*   qk   = (u16*)(ws + 64 * MB);    // 32MB [8192,2048] (q|k)
  u16*   h2   = (u16*)(ws + 96 * MB);    // 16MB
  u16*   vT   = (u16*)(ws + 112 * MB);   // 16MB [4][1024][2048]
  u16*   w1T  = (u16*)(ws + 144 * MB);   //  8MB [4096,1024]
  u16*   w2T  = (u16*)(ws + 152 * MB);   //  8MB [1024,4096]
  u16*   r2   = (u16*)(ws + 160 * MB);   // 16MB fp16 [8192,1024]
  u16*   g    = (u16*)(ws + 0);          // 64MB [8192,4096] (sc/P dead)

  dim3 blk(256);

  // 1) LN1 -> h fp16
  ln_k<true><<<2048, blk, 0, stream>>>(x, ln1_g, ln1_b, h);
  // 2) w_qkv [1024,3072] -> wqkT [3072,1024] fp16
  transpose_k<<<dim3(3072 / 32, 1024 / 32, 1), blk, 0, stream>>>(w_qkv, wqkT,
                                                                 1024, 3072);
  // 3) qkv-GEMM: h @ wqkv^T -> qk (n<2048) + vT DIRECT.  grid 1536.
  gemm_nt<0, true><<<dim3(24, 64, 1), blk, 0, stream>>>(
      h, wqkT, 8192, 3072, 1024, 1024, 1024, 0, 0, 0, nullptr, qk, vT,
      nullptr, nullptr);
  // 4) GEMM2: scores[z] = q[z] @ k[z]^T (K=1024).  grid 256/z.
  gemm_nt<1, true><<<dim3(16, 16, 4), blk, 0, stream>>>(
      qk, qk + 1024, 2048, 2048, 1024, 2048, 2048, 2048L * 2048, 2048L * 2048,
      2048L * 2048, sc, nullptr, nullptr, nullptr, nullptr);
  // 5) softmax in-place: P (fp16, lda=4096 u16) overwrites score rows
  softmax_k<<<8192, blk, 0, stream>>>(sc);
  // 6) GEMM3: attn = P @ vT + resid(x f32) -> r2 fp16.  grid 128/z.
  gemm_nt<2, true><<<dim3(8, 16, 4), blk, 0, stream>>>(
      (const u16*)sc, vT, 2048, 1024, 2048, 4096, 2048, 2048L * 4096,
      1024L * 2048, 2048L * 1024, nullptr, r2, nullptr, x, nullptr);
  // 7) LN2 (fp16 in) -> h2 fp16
  ln_k<false><<<2048, blk, 0, stream>>>(r2, ln2_g, ln2_b, h2);
  // 8) fc1_w -> w1T, fc2_w -> w2T
  transpose_k<<<dim3(4096 / 32, 1024 / 32, 1), blk, 0, stream>>>(fc1_w, w1T,
                                                                 1024, 4096);
  transpose_k<<<dim3(1024 / 32, 4096 / 32, 1), blk, 0, stream>>>(fc2_w, w2T,
                                                                 4096, 1024);
  // 9) GEMM4: g = gelu(h2 @ fc1_w + b1) fp16.  grid 2048.
  gemm_nt<3, true><<<dim3(32, 64, 1), blk, 0, stream>>>(
      h2, w1T, 8192, 4096, 1024, 1024, 1024, 0, 0, 0, nullptr, g, nullptr,
      fc1_b, nullptr);
  // 10) GEMM5: out = g @ fc2_w + b2 + r2(fp16).  grid 512.
  gemm_nt<4, true><<<dim3(8, 64, 1), blk, 0, stream>>>(
      g, w2T, 8192, 1024, 4096, 4096, 4096, 0, 0, 0, out, nullptr, nullptr,
      fc2_b, r2);
}